// Round 6
// baseline (240.571 us; speedup 1.0000x reference)
//
#include <hip/hip_runtime.h>
#include <hip/hip_bf16.h>

// B=2, S=4096, H=768, NH=12, HD=64
typedef float f32x4 __attribute__((ext_vector_type(4)));
typedef float f32x16 __attribute__((ext_vector_type(16)));
typedef short short8 __attribute__((ext_vector_type(8)));

#define LOG2E 1.44269504088896340736f

__device__ __forceinline__ ushort f2bf(float f){
  unsigned u = __builtin_bit_cast(unsigned, f);
  u = (u + 0x7fffu + ((u >> 16) & 1u)) >> 16;
  return (ushort)u;
}

// hardware exp2 (schedulable, no volatile)
__device__ __forceinline__ float exp2_hw(float x){
  float r; asm("v_exp_f32 %0, %1" : "=v"(r) : "v"(x)); return r;
}

// pack two f32 -> bf16x2 with round-half-up (2 adds + 1 v_perm)
__device__ __forceinline__ uint pack_bf16_rh(float lo, float hi){
  uint ul = __builtin_bit_cast(uint, lo) + 0x8000u;
  uint uh = __builtin_bit_cast(uint, hi) + 0x8000u;
  return __builtin_amdgcn_perm(uh, ul, 0x07060302u);
}

__device__ __forceinline__ float fmax3(float a, float b, float c){
  return fmaxf(fmaxf(a, b), c);   // clang fuses to v_max3_f32
}

__global__ void cvt_kernel(const float* __restrict__ src, ushort* __restrict__ dst, int n4){
  int i = blockIdx.x * 256 + threadIdx.x;
  if (i < n4){
    float4 v = ((const float4*)src)[i];
    ushort4 o; o.x = f2bf(v.x); o.y = f2bf(v.y); o.z = f2bf(v.z); o.w = f2bf(v.w);
    ((ushort4*)dst)[i] = o;
  }
}

__global__ void scale_kernel(const float* __restrict__ src, float* __restrict__ dst,
                             float sc, int n){
  int i = blockIdx.x * 256 + threadIdx.x;
  if (i < n) dst[i] = src[i] * sc;
}

// Out[m,n] = (sum_k X[m,k]*W[n,k] + bias[n]) * scale
__global__ __launch_bounds__(256) void qkv_gemm(const ushort* __restrict__ Xb,
                                                const ushort* __restrict__ Wb,
                                                const float* __restrict__ bias,
                                                ushort* __restrict__ Out,
                                                float scale){
  __shared__ ushort Xs[128*64];
  __shared__ ushort Ws[128*64];
  const int m0 = blockIdx.x * 128, n0 = blockIdx.y * 128;
  const int tid = threadIdx.x, w = tid >> 6, lane = tid & 63;
  const int r = lane & 15, g = lane >> 4;
  const int wr = (w >> 1) * 64, wc = (w & 1) * 64;
  f32x4 acc[4][4] = {};
  for (int k0 = 0; k0 < 768; k0 += 64){
    #pragma unroll
    for (int p = 0; p < 4; p++){
      int c = tid + 256*p; int row = c >> 3, cir = c & 7;
      uint4 vx = *(const uint4*)(Xb + (size_t)(m0+row)*768 + k0 + cir*8);
      *(uint4*)((char*)Xs + row*128 + ((cir*16) ^ ((row&7)<<4))) = vx;
      uint4 vw = *(const uint4*)(Wb + (size_t)(n0+row)*768 + k0 + cir*8);
      *(uint4*)((char*)Ws + row*128 + ((cir*16) ^ ((row&7)<<4))) = vw;
    }
    __syncthreads();
    #pragma unroll
    for (int ks = 0; ks < 2; ks++){
      short8 af[4], bf[4];
      int bo = ks*64 + g*16;
      #pragma unroll
      for (int i = 0; i < 4; i++){
        int rowa = wr + i*16 + r;
        af[i] = *(const short8*)((char*)Xs + rowa*128 + (bo ^ ((rowa&7)<<4)));
        int rowb = wc + i*16 + r;
        bf[i] = *(const short8*)((char*)Ws + rowb*128 + (bo ^ ((rowb&7)<<4)));
      }
      #pragma unroll
      for (int i = 0; i < 4; i++)
        #pragma unroll
        for (int j = 0; j < 4; j++)
          acc[i][j] = __builtin_amdgcn_mfma_f32_16x16x32_bf16(af[i], bf[j], acc[i][j], 0,0,0);
    }
    __syncthreads();
  }
  #pragma unroll
  for (int i = 0; i < 4; i++){
    #pragma unroll
    for (int j = 0; j < 4; j++){
      int col = n0 + wc + j*16 + r;
      float bv = bias[col];
      int rowb = m0 + wr + i*16 + g*4;
      #pragma unroll
      for (int q = 0; q < 4; q++)
        Out[(size_t)(rowb+q)*768 + col] = f2bf((acc[i][j][q] + bv) * scale);
    }
  }
}

// Same GEMM but writes output TRANSPOSED: Vt[(token>>12)*768 + col][token&4095]
__global__ __launch_bounds__(256) void qkv_gemm_vt(const ushort* __restrict__ Xb,
                                                   const ushort* __restrict__ Wb,
                                                   const float* __restrict__ bias,
                                                   ushort* __restrict__ VtOut){
  __shared__ ushort Xs[128*64];
  __shared__ ushort Ws[128*64];
  const int m0 = blockIdx.x * 128, n0 = blockIdx.y * 128;
  const int tid = threadIdx.x, w = tid >> 6, lane = tid & 63;
  const int r = lane & 15, g = lane >> 4;
  const int wr = (w >> 1) * 64, wc = (w & 1) * 64;
  f32x4 acc[4][4] = {};
  for (int k0 = 0; k0 < 768; k0 += 64){
    #pragma unroll
    for (int p = 0; p < 4; p++){
      int c = tid + 256*p; int row = c >> 3, cir = c & 7;
      uint4 vx = *(const uint4*)(Xb + (size_t)(m0+row)*768 + k0 + cir*8);
      *(uint4*)((char*)Xs + row*128 + ((cir*16) ^ ((row&7)<<4))) = vx;
      uint4 vw = *(const uint4*)(Wb + (size_t)(n0+row)*768 + k0 + cir*8);
      *(uint4*)((char*)Ws + row*128 + ((cir*16) ^ ((row&7)<<4))) = vw;
    }
    __syncthreads();
    #pragma unroll
    for (int ks = 0; ks < 2; ks++){
      short8 af[4], bf[4];
      int bo = ks*64 + g*16;
      #pragma unroll
      for (int i = 0; i < 4; i++){
        int rowa = wr + i*16 + r;
        af[i] = *(const short8*)((char*)Xs + rowa*128 + (bo ^ ((rowa&7)<<4)));
        int rowb = wc + i*16 + r;
        bf[i] = *(const short8*)((char*)Ws + rowb*128 + (bo ^ ((rowb&7)<<4)));
      }
      #pragma unroll
      for (int i = 0; i < 4; i++)
        #pragma unroll
        for (int j = 0; j < 4; j++)
          acc[i][j] = __builtin_amdgcn_mfma_f32_16x16x32_bf16(af[i], bf[j], acc[i][j], 0,0,0);
    }
    __syncthreads();
  }
  #pragma unroll
  for (int i = 0; i < 4; i++){
    #pragma unroll
    for (int j = 0; j < 4; j++){
      int col = n0 + wc + j*16 + r;
      float bv = bias[col];
      int rowb = m0 + wr + i*16 + g*4;  // 4 consecutive tokens
      ushort4 o;
      o.x = f2bf(acc[i][j][0] + bv);
      o.y = f2bf(acc[i][j][1] + bv);
      o.z = f2bf(acc[i][j][2] + bv);
      o.w = f2bf(acc[i][j][3] + bv);
      size_t vrow = (size_t)((rowb >> 12) * 768 + col);
      *(ushort4*)(VtOut + vrow * 4096 + (rowb & 4095)) = o;
    }
  }
}

// Flash attention, 32x32 MFMA, S^T orientation, log2-domain softmax, in-register P.
// Block = 128 q x (b,h); 4 waves x 32 q. Q pre-scaled by 0.125*log2e; mask pre-scaled
// by log2e. V pre-transposed in global. Defer-max THR = 8*log2e. P never touches LDS:
// packed to bf16 pairs and redistributed with v_permlane32_swap_b32 (lane^32 dword swap).
__global__ __launch_bounds__(256, 3) void flash_attn(const ushort* __restrict__ Qb,
                                                     const ushort* __restrict__ Kb,
                                                     const ushort* __restrict__ Vt,
                                                     const float* __restrict__ maskL,
                                                     float* __restrict__ out){
  __shared__ ushort Ks[64*64];    // [kv][d] swizzled
  __shared__ ushort Vts[64*64];   // [d][kv] swizzled
  const int tid = threadIdx.x, w = tid >> 6, lane = tid & 63;
  const int q = lane & 31, hi = lane >> 5;
  const int swq = (q & 7) << 4;
  const int h = blockIdx.y, b = blockIdx.z;
  const int q0 = blockIdx.x * 128 + w * 32;

  // Q B-frags (32x32x16): col=q=lane&31, k = 8*hi + j; bq[kd] covers d = 16*kd..+15
  short8 bq[4];
  {
    const ushort* qp = Qb + (size_t)(b*4096 + q0 + q)*768 + h*64 + hi*8;
    #pragma unroll
    for (int kd = 0; kd < 4; kd++) bq[kd] = *(const short8*)(qp + 16*kd);
  }
  const ushort* Kbase = Kb + (size_t)(b*4096)*768 + h*64;
  const ushort* Vbase = Vt + (size_t)(b*768 + h*64)*4096;

  const int row0 = tid >> 3, cir = tid & 7;
  const int row1 = row0 + 32;

  uint4 kreg0, kreg1, vreg0, vreg1;
  kreg0 = *(const uint4*)(Kbase + (size_t)row0*768 + cir*8);
  kreg1 = *(const uint4*)(Kbase + (size_t)row1*768 + cir*8);
  vreg0 = *(const uint4*)(Vbase + (size_t)row0*4096 + cir*8);
  vreg1 = *(const uint4*)(Vbase + (size_t)row1*4096 + cir*8);

  f32x16 ctx[2] = {};
  float mrun = -1e30f, lrun = 0.f;

  for (int t = 0; t < 64; t++){
    const int kv0 = t * 64;
    *(uint4*)((char*)Ks  + row0*128 + ((cir*16) ^ ((row0&7)<<4))) = kreg0;
    *(uint4*)((char*)Ks  + row1*128 + ((cir*16) ^ ((row1&7)<<4))) = kreg1;
    *(uint4*)((char*)Vts + row0*128 + ((cir*16) ^ ((row0&7)<<4))) = vreg0;
    *(uint4*)((char*)Vts + row1*128 + ((cir*16) ^ ((row1&7)<<4))) = vreg1;
    __syncthreads();
    if (t < 63){
      const int kn = kv0 + 64;
      kreg0 = *(const uint4*)(Kbase + (size_t)(kn+row0)*768 + cir*8);
      kreg1 = *(const uint4*)(Kbase + (size_t)(kn+row1)*768 + cir*8);
      vreg0 = *(const uint4*)(Vbase + (size_t)row0*4096 + kn + cir*8);
      vreg1 = *(const uint4*)(Vbase + (size_t)row1*4096 + kn + cir*8);
    }
    // S^T strips: sc[s] (32x32 C-layout): col=q, kv = 32s + (e&3) + 8*(e>>2) + 4*hi
    f32x16 sc[2];
    #pragma unroll
    for (int s = 0; s < 2; s++){
      f32x16 z = {};
      #pragma unroll
      for (int kd = 0; kd < 4; kd++){
        int row = s*32 + q;
        short8 ak = *(const short8*)((char*)Ks + row*128 + ((32*kd + 16*hi) ^ swq));
        z = __builtin_amdgcn_mfma_f32_32x32x16_bf16(ak, bq[kd], z, 0,0,0);
      }
      sc[s] = z;
    }
    // + mask (log2-scaled), per e-quad: kv = 32s + 8eq + 4hi + {0..3}
    #pragma unroll
    for (int s = 0; s < 2; s++)
      #pragma unroll
      for (int eq = 0; eq < 4; eq++){
        float4 mv = *(const float4*)(maskL + b*4096 + kv0 + s*32 + eq*8 + hi*4);
        sc[s][4*eq+0] += mv.x; sc[s][4*eq+1] += mv.y;
        sc[s][4*eq+2] += mv.z; sc[s][4*eq+3] += mv.w;
      }
    // max over the lane's 32 values + lane^32 exchange
    float ma = fmax3(sc[0][0], sc[0][1], sc[0][2]);
    float mb = fmax3(sc[0][3], sc[0][4], sc[0][5]);
    ma = fmax3(ma, sc[0][6], sc[0][7]);
    mb = fmax3(mb, sc[0][8], sc[0][9]);
    ma = fmax3(ma, sc[0][10], sc[0][11]);
    mb = fmax3(mb, sc[0][12], sc[0][13]);
    ma = fmax3(ma, sc[0][14], sc[0][15]);
    #pragma unroll
    for (int e = 0; e < 15; e += 3) mb = fmax3(mb, sc[1][e], sc[1][e+1]);
    ma = fmax3(ma, sc[1][2], sc[1][5]);
    ma = fmax3(ma, sc[1][8], sc[1][11]);
    ma = fmax3(ma, sc[1][14], sc[1][15]);
    float mt = fmaxf(ma, mb);
    mt = fmaxf(mt, __shfl_xor(mt, 32, 64));
    // defer-max: rescale only when tile max grew > 8*log2e (log2 units)
    if (!__all(mt <= mrun + 11.5415603f)){
      float mnew = fmaxf(mrun, mt);
      float alpha = exp2_hw(mrun - mnew);
      mrun = mnew;
      lrun *= alpha;
      #pragma unroll
      for (int s = 0; s < 2; s++)
        #pragma unroll
        for (int e = 0; e < 16; e++) ctx[s][e] *= alpha;
    }
    float rs = 0.f;
    #pragma unroll
    for (int s = 0; s < 2; s++)
      #pragma unroll
      for (int e = 0; e < 16; e++){
        float pv = exp2_hw(sc[s][e] - mrun); sc[s][e] = pv; rs += pv;
      }
    rs += __shfl_xor(rs, 32, 64);
    lrun += rs;
    // pack P to bf16 dwords and build PV B-frags in-register via permlane32_swap.
    // strip s: wu[u] = kv pair (32s + 4hi + [u>=2?8:0]*... ) -- see derivation:
    // w[4u2+0]=(e0,e1), w[4u2+1]=(e2,e3), w[4u2+2]=(e4,e5), w[4u2+3]=(e6,e7) per half
    short8 bp[4];
    #pragma unroll
    for (int s = 0; s < 2; s++){
      uint pw[8];
      #pragma unroll
      for (int u = 0; u < 8; u++)
        pw[u] = pack_bf16_rh(sc[s][2*u], sc[s][2*u+1]);
      #pragma unroll
      for (int u2 = 0; u2 < 2; u2++){
        uint x0 = pw[4*u2+0], x1 = pw[4*u2+1], x2 = pw[4*u2+2], x3 = pw[4*u2+3];
        asm("v_permlane32_swap_b32 %0, %1" : "+v"(x0), "+v"(x2));
        asm("v_permlane32_swap_b32 %0, %1" : "+v"(x1), "+v"(x3));
        union { uint u[4]; short8 v; } bb;
        bb.u[0] = x0; bb.u[1] = x1; bb.u[2] = x2; bb.u[3] = x3;
        bp[2*s + u2] = bb.v;
      }
    }
    // ctx^T[d,q] += V^T[d,kv] * P[kv,q]; A-frag row=d=32sd+q(lane&31), k=kv=16kk+8hi+j
    #pragma unroll
    for (int sd = 0; sd < 2; sd++){
      int row = sd*32 + q;
      #pragma unroll
      for (int kk = 0; kk < 4; kk++){
        short8 av = *(const short8*)((char*)Vts + row*128 + ((32*kk + 16*hi) ^ swq));
        ctx[sd] = __builtin_amdgcn_mfma_f32_32x32x16_bf16(av, bp[kk], ctx[sd], 0,0,0);
      }
    }
    __syncthreads();
  }
  // epilogue: lane q holds d = 32sd + 8eq + 4hi + {0..3} -> float4 stores
  float inv = 1.0f / lrun;
  size_t orow = (size_t)(b*4096 + q0 + q) * 768 + h*64;
  #pragma unroll
  for (int sd = 0; sd < 2; sd++)
    #pragma unroll
    for (int eq = 0; eq < 4; eq++){
      float4 o;
      o.x = ctx[sd][4*eq+0] * inv; o.y = ctx[sd][4*eq+1] * inv;
      o.z = ctx[sd][4*eq+2] * inv; o.w = ctx[sd][4*eq+3] * inv;
      *(float4*)(out + orow + sd*32 + eq*8 + hi*4) = o;
    }
}

extern "C" void kernel_launch(void* const* d_in, const int* in_sizes, int n_in,
                              void* d_out, int out_size, void* d_ws, size_t ws_size,
                              hipStream_t stream){
  const float* hidden = (const float*)d_in[0];
  const float* mask   = (const float*)d_in[1];
  const float* Wq     = (const float*)d_in[2];
  const float* bq     = (const float*)d_in[3];
  const float* Wk     = (const float*)d_in[4];
  const float* bk     = (const float*)d_in[5];
  const float* Wv     = (const float*)d_in[6];
  const float* bv     = (const float*)d_in[7];
  char* ws = (char*)d_ws;
  ushort* Xb    = (ushort*)(ws);
  ushort* Wqb   = (ushort*)(ws + 12582912);
  ushort* Wkb   = (ushort*)(ws + 13762560);
  ushort* Wvb   = (ushort*)(ws + 14942208);
  ushort* Qb    = (ushort*)(ws + 16121856);
  ushort* Kb    = (ushort*)(ws + 28704768);
  ushort* Vtb   = (ushort*)(ws + 41287680);  // [1536][4096] bf16 transposed V
  float*  maskL = (float*)(ws + 53870592);   // mask * log2e, 8192 f32

  cvt_kernel<<<6144, 256, 0, stream>>>(hidden, Xb, 1572864);
  cvt_kernel<<<576, 256, 0, stream>>>(Wq, Wqb, 147456);
  cvt_kernel<<<576, 256, 0, stream>>>(Wk, Wkb, 147456);
  cvt_kernel<<<576, 256, 0, stream>>>(Wv, Wvb, 147456);
  scale_kernel<<<32, 256, 0, stream>>>(mask, maskL, LOG2E, 8192);

  dim3 gg(64, 6);
  qkv_gemm<<<gg, 256, 0, stream>>>(Xb, Wqb, bq, Qb, 0.125f * LOG2E);
  qkv_gemm<<<gg, 256, 0, stream>>>(Xb, Wkb, bk, Kb, 1.0f);
  qkv_gemm_vt<<<gg, 256, 0, stream>>>(Xb, Wvb, bv, Vtb);

  dim3 ga(32, 12, 2);
  flash_attn<<<ga, 256, 0, stream>>>(Qb, Kb, Vtb, maskL, (float*)d_out);
}